// Round 7
// baseline (953.444 us; speedup 1.0000x reference)
//
#include <hip/hip_runtime.h>

#define DIN 128
#define NHEADS 4
#define CH 32
#define MT 128          // GEMM rows per block
#define CHUNK 4096      // node-scan chunk per block
#define NPB 256         // nodes per bucket (bucket = dst >> 8)
#define EPB_IT 25       // edges per thread in scatter phase (block chunk: 6400)
#define CSR_GRID 512    // blocks in fused CSR kernel (guaranteed co-resident)

typedef _Float16 h8 __attribute__((ext_vector_type(8)));
typedef float f4 __attribute__((ext_vector_type(4)));

// ---------------------------------------------------------------------------
// Grid-wide barrier: dedicated counter per sync point (no generation logic).
// Device-scope RMW for arrive+spin; fences for release/acquire. Co-residency
// guaranteed by __launch_bounds__(256,4): >=4 blocks/CU * 256 CUs >= CSR_GRID.
// ---------------------------------------------------------------------------
__device__ __forceinline__ void gsync(int* bar, int idx, int nblk) {
    __syncthreads();
    if (threadIdx.x == 0) {
        __threadfence();
        atomicAdd(&bar[idx], 1);
        while (atomicAdd(&bar[idx], 0) < nblk)
            __builtin_amdgcn_s_sleep(2);
    }
    __syncthreads();
    __threadfence();
}

// ---------------------------------------------------------------------------
// Fused CSR-build kernel (replaces 8 dispatches):
//  P0 prep_w (W fp32 -> Wt[mat][n][k] fp16)          P5 chunk partial sums
//  P1 bucket histogram                                P6 scan chunk partials
//  P2 bucket offsets scan                             P7 write rowptr
//  P3 bucket scatter (coalesced pair runs)            P8 place srcs (LDS cursors)
//  P4 per-node counts (LDS only)
// ---------------------------------------------------------------------------
__global__ __launch_bounds__(256, 4) void coop_csr(
    const float* __restrict__ Wq, const float* __restrict__ Wk,
    const float* __restrict__ Wv, const float* __restrict__ Wsk,
    _Float16* __restrict__ wt,
    const int* __restrict__ ei, uint2* __restrict__ pairs,
    int* __restrict__ sorted, int* __restrict__ counts,
    int* __restrict__ rowptr, int* __restrict__ bar, int* __restrict__ bcnt,
    int* __restrict__ boff, int* __restrict__ bcur,
    int* __restrict__ partials, int* __restrict__ chunkoff,
    int E, int N, int nb, int nch)
{
    __shared__ int smem[512];
    __shared__ int ws[8];
    const int b = blockIdx.x, t = threadIdx.x;
    const int nblk = gridDim.x;

    // ---- P0: prep_w (strided over 4*128*128 elements) ----
    for (int i = b * 256 + t; i < 4 * 16384; i += nblk * 256) {
        int mat = i >> 14;
        int rem = i & 16383;
        int n  = rem >> 7;
        int kk = rem & 127;
        const float* W = (mat == 0) ? Wq : (mat == 1) ? Wk : (mat == 2) ? Wv : Wsk;
        wt[i] = (_Float16)W[kk * 128 + n];
    }
    gsync(bar, 0, nblk);

    // ---- P1: bucket histogram ----
    for (int i = t; i < nb; i += 256) smem[i] = 0;
    __syncthreads();
    for (long long i = (long long)b * 256 + t; i < E; i += (long long)nblk * 256)
        atomicAdd(&smem[ei[(size_t)E + i] >> 8], 1);
    __syncthreads();
    for (int i = t; i < nb; i += 256)
        if (smem[i]) atomicAdd(&bcnt[i], smem[i]);
    gsync(bar, 1, nblk);

    // ---- P2: exclusive scan of bucket counts (block 0; pairs of values) ----
    if (b == 0) {
        int i0 = 2 * t, i1 = 2 * t + 1;
        int a = (i0 < nb) ? bcnt[i0] : 0;
        int c = (i1 < nb) ? bcnt[i1] : 0;
        int s = a + c;
        int lane = t & 63, wid = t >> 6;
        int incl = s;
        #pragma unroll
        for (int off = 1; off < 64; off <<= 1) {
            int n = __shfl_up(incl, off);
            if (lane >= off) incl += n;
        }
        if (lane == 63) ws[wid] = incl;
        __syncthreads();
        int add = 0;
        for (int w = 0; w < wid; ++w) add += ws[w];
        int excl = incl - s + add;
        if (i0 < nb) { boff[i0] = excl;     bcur[i0] = excl; }
        if (i1 < nb) { boff[i1] = excl + a; bcur[i1] = excl + a; }
        if (t == 255) boff[nb] = excl + s;   // grand total (tail threads add 0)
    }
    gsync(bar, 2, nblk);

    // ---- P3: scatter (src,dst) into bucket regions, coalesced runs ----
    for (long long c0 = (long long)b * (256 * EPB_IT); c0 < E;
         c0 += (long long)nblk * (256 * EPB_IT)) {
        for (int i = t; i < nb; i += 256) smem[i] = 0;
        __syncthreads();
        int ps[EPB_IT], pd[EPB_IT];
        #pragma unroll
        for (int j = 0; j < EPB_IT; ++j) {
            long long e = c0 + j * 256 + t;
            if (e < E) {
                ps[j] = ei[e];
                pd[j] = ei[(size_t)E + e];
                atomicAdd(&smem[pd[j] >> 8], 1);
            } else pd[j] = -1;
        }
        __syncthreads();
        for (int i = t; i < nb; i += 256) {
            int c = smem[i];
            if (c) smem[i] = atomicAdd(&bcur[i], c);
        }
        __syncthreads();
        #pragma unroll
        for (int j = 0; j < EPB_IT; ++j) {
            if (pd[j] >= 0) {
                int pos = atomicAdd(&smem[pd[j] >> 8], 1);
                pairs[pos] = make_uint2((unsigned)ps[j], (unsigned)pd[j]);
            }
        }
        __syncthreads();
    }
    gsync(bar, 3, nblk);

    // ---- P4: per-node counts (one bucket per block, LDS atomics only) ----
    for (int bb = b; bb < nb; bb += nblk) {
        smem[t] = 0;
        __syncthreads();
        int s = boff[bb], e = boff[bb + 1];
        for (int i = s + t; i < e; i += 256)
            atomicAdd(&smem[pairs[i].y & (NPB - 1)], 1);
        __syncthreads();
        int node = bb * NPB + t;
        if (node < N) counts[node] = smem[t];
        __syncthreads();
    }
    gsync(bar, 4, nblk);

    // ---- P5: chunk partial sums ----
    if (b < nch) {
        int base = b * CHUNK + t * 16;
        int s = 0;
        #pragma unroll
        for (int j = 0; j < 16; ++j) {
            int i = base + j;
            if (i < N) s += counts[i];
        }
        #pragma unroll
        for (int off = 1; off < 64; off <<= 1) s += __shfl_xor(s, off);
        int lane = t & 63, wid = t >> 6;
        if (lane == 0) ws[wid] = s;
        __syncthreads();
        if (t == 0) partials[b] = ws[0] + ws[1] + ws[2] + ws[3];
    }
    gsync(bar, 5, nblk);

    // ---- P6: scan chunk partials (block 0, single wave; nch <= 64) ----
    if (b == 0 && t < 64) {
        int v = (t < nch) ? partials[t] : 0;
        int s = v;
        #pragma unroll
        for (int off = 1; off < 64; off <<= 1) {
            int n = __shfl_up(s, off);
            if (t >= off) s += n;
        }
        if (t < nch) chunkoff[t] = s - v;
    }
    gsync(bar, 6, nblk);

    // ---- P7: write rowptr ----
    if (b < nch) {
        int base = b * CHUNK + t * 16;
        int vals[16];
        int s = 0;
        #pragma unroll
        for (int j = 0; j < 16; ++j) {
            int i = base + j;
            vals[j] = (i < N) ? counts[i] : 0;
            s += vals[j];
        }
        int lane = t & 63, wid = t >> 6;
        int incl = s;
        #pragma unroll
        for (int off = 1; off < 64; off <<= 1) {
            int n = __shfl_up(incl, off);
            if (lane >= off) incl += n;
        }
        if (lane == 63) ws[wid] = incl;
        __syncthreads();
        int add = chunkoff[b];
        for (int w = 0; w < wid; ++w) add += ws[w];
        int run = incl - s + add;
        #pragma unroll
        for (int j = 0; j < 16; ++j) {
            int i = base + j;
            if (i < N) rowptr[i + 1] = run + vals[j];
            run += vals[j];
        }
        if (b == 0 && t == 0) rowptr[0] = 0;
    }
    gsync(bar, 7, nblk);

    // ---- P8: final placement (LDS cursors; writes in ~16KB bucket window) ----
    for (int bb = b; bb < nb; bb += nblk) {
        int node = bb * NPB + t;
        smem[t] = (node < N) ? rowptr[node] : 0;
        __syncthreads();
        int s = boff[bb], e = boff[bb + 1];
        for (int i = s + t; i < e; i += 256) {
            uint2 pr = pairs[i];
            int pos = atomicAdd(&smem[pr.y & (NPB - 1)], 1);
            sorted[pos] = (int)pr.x;
        }
        __syncthreads();
    }
}

// ---------------------------------------------------------------------------
// MFMA GEMM, cvt fused: reads x fp32, converts in LDS staging; loops 4 mats
// per block (A-tile reused). mats 1/2 write interleaved kv rows.
// ---------------------------------------------------------------------------
__global__ __launch_bounds__(256) void qkvs_mfma(
    const float* __restrict__ x, const _Float16* __restrict__ wt,
    const float* __restrict__ bq, const float* __restrict__ bk,
    const float* __restrict__ bv, const float* __restrict__ bsk,
    _Float16* __restrict__ qh, _Float16* __restrict__ kvh,
    float* __restrict__ outskip, int N)
{
    __shared__ _Float16 As[MT * 128];            // 32 KB
    const int t = threadIdx.x;
    const int rowBase = blockIdx.x * MT;

    // stage A with on-the-fly fp32->fp16: chunk (r, c8) = 8 halves
    const float4* x4 = reinterpret_cast<const float4*>(x);
    for (int i = t; i < MT * 16; i += 256) {
        int r  = i >> 4;
        int c8 = i & 15;
        h8 hv = {};
        int gr = rowBase + r;
        if (gr < N) {
            float4 f0 = x4[(size_t)gr * 32 + c8 * 2];
            float4 f1 = x4[(size_t)gr * 32 + c8 * 2 + 1];
            hv[0] = (_Float16)f0.x; hv[1] = (_Float16)f0.y;
            hv[2] = (_Float16)f0.z; hv[3] = (_Float16)f0.w;
            hv[4] = (_Float16)f1.x; hv[5] = (_Float16)f1.y;
            hv[6] = (_Float16)f1.z; hv[7] = (_Float16)f1.w;
        }
        *reinterpret_cast<h8*>(&As[r * 128 + ((c8 ^ (r & 7)) << 3)]) = hv;
    }
    __syncthreads();

    const int wid  = t >> 6;
    const int l    = t & 63;
    const int lm   = l & 15;
    const int quad = l >> 4;

    for (int mat = 0; mat < 4; ++mat) {
        const _Float16* __restrict__ Bsrc = wt + (size_t)mat * 16384;

        f4 acc[2][8];
        #pragma unroll
        for (int ms = 0; ms < 2; ++ms)
            #pragma unroll
            for (int nt = 0; nt < 8; ++nt)
                acc[ms][nt] = (f4){0.f, 0.f, 0.f, 0.f};

        #pragma unroll
        for (int kq = 0; kq < 4; ++kq) {
            const int c8 = kq * 4 + quad;
            const int k0 = c8 << 3;
            h8 a0 = *reinterpret_cast<const h8*>(
                &As[(wid * 32 + lm) * 128 + ((c8 ^ (lm & 7)) << 3)]);
            h8 a1 = *reinterpret_cast<const h8*>(
                &As[(wid * 32 + 16 + lm) * 128 + ((c8 ^ (lm & 7)) << 3)]);
            #pragma unroll
            for (int nt = 0; nt < 8; ++nt) {
                h8 bfr = *reinterpret_cast<const h8*>(
                    &Bsrc[(size_t)(nt * 16 + lm) * 128 + k0]);
                acc[0][nt] = __builtin_amdgcn_mfma_f32_16x16x32_f16(a0, bfr, acc[0][nt], 0, 0, 0);
                acc[1][nt] = __builtin_amdgcn_mfma_f32_16x16x32_f16(a1, bfr, acc[1][nt], 0, 0, 0);
            }
        }

        const float* bias = (mat == 0) ? bq : (mat == 1) ? bk : (mat == 2) ? bv : bsk;

        #pragma unroll
        for (int ms = 0; ms < 2; ++ms) {
            #pragma unroll
            for (int nt = 0; nt < 8; ++nt) {
                int col = nt * 16 + lm;
                float bsv = bias[col];
                #pragma unroll
                for (int i2 = 0; i2 < 4; ++i2) {
                    int row = rowBase + wid * 32 + ms * 16 + quad * 4 + i2;
                    if (row < N) {
                        float val = acc[ms][nt][i2] + bsv;
                        if (mat == 3)
                            outskip[(size_t)row * 128 + col] = val;
                        else if (mat == 0)
                            qh[(size_t)row * 128 + col] = (_Float16)val;
                        else {
                            size_t off = (size_t)row * 256 + ((col >> 2) << 3)
                                       + (col & 3) + ((mat == 2) ? 4 : 0);
                            kvh[off] = (_Float16)val;
                        }
                    }
                }
            }
        }
    }
}

// ---------------------------------------------------------------------------
// Fused logits + softmax + aggregation (unchanged from R6)
// ---------------------------------------------------------------------------
__device__ inline float4 cvt4(uint2 r) {
    union { uint2 u; _Float16 h[4]; } c;
    c.u = r;
    return make_float4((float)c.h[0], (float)c.h[1], (float)c.h[2], (float)c.h[3]);
}

__global__ __launch_bounds__(256) void node_aggregate(
    const _Float16* __restrict__ q, const _Float16* __restrict__ kv,
    const int* __restrict__ rowptr, const int* __restrict__ srcs,
    float* __restrict__ out, int N)
{
    int gid  = blockIdx.x * 256 + threadIdx.x;
    int node = gid >> 5;
    if (node >= N) return;
    int l = gid & 31;

    float4 qv = cvt4(reinterpret_cast<const uint2*>(q + (size_t)node * 128)[l]);
    float4 acc = make_float4(0.f, 0.f, 0.f, 0.f);
    float z = 0.f;

    const uint4* kv4 = reinterpret_cast<const uint4*>(kv);
    const float SC = 0.17677669529663687f;   // 1/sqrt(32)
    int e0 = rowptr[node], e1 = rowptr[node + 1];
    int e = e0;
    for (; e + 4 <= e1; e += 4) {
        int s0 = srcs[e], s1 = srcs[e + 1], s2 = srcs[e + 2], s3 = srcs[e + 3];
        uint4 r0 = kv4[(size_t)s0 * 32 + l];
        uint4 r1 = kv4[(size_t)s1 * 32 + l];
        uint4 r2 = kv4[(size_t)s2 * 32 + l];
        uint4 r3 = kv4[(size_t)s3 * 32 + l];
        float4 k0 = cvt4(make_uint2(r0.x, r0.y)), v0 = cvt4(make_uint2(r0.z, r0.w));
        float4 k1 = cvt4(make_uint2(r1.x, r1.y)), v1 = cvt4(make_uint2(r1.z, r1.w));
        float4 k2 = cvt4(make_uint2(r2.x, r2.y)), v2 = cvt4(make_uint2(r2.z, r2.w));
        float4 k3 = cvt4(make_uint2(r3.x, r3.y)), v3 = cvt4(make_uint2(r3.z, r3.w));
        float sa = qv.x * k0.x + qv.y * k0.y + qv.z * k0.z + qv.w * k0.w;
        float sb = qv.x * k1.x + qv.y * k1.y + qv.z * k1.z + qv.w * k1.w;
        float sc = qv.x * k2.x + qv.y * k2.y + qv.z * k2.z + qv.w * k2.w;
        float sd = qv.x * k3.x + qv.y * k3.y + qv.z * k3.z + qv.w * k3.w;
        sa += __shfl_xor(sa, 1); sb += __shfl_xor(sb, 1);
        sc += __shfl_xor(sc, 1); sd += __shfl_xor(sd, 1);
        sa += __shfl_xor(sa, 2); sb += __shfl_xor(sb, 2);
        sc += __shfl_xor(sc, 2); sd += __shfl_xor(sd, 2);
        sa += __shfl_xor(sa, 4); sb += __shfl_xor(sb, 4);
        sc += __shfl_xor(sc, 4); sd += __shfl_xor(sd, 4);
        float pa = __expf(sa * SC), pb = __expf(sb * SC);
        float pc = __expf(sc * SC), pdd = __expf(sd * SC);
        z += (pa + pb) + (pc + pdd);
        acc.x += pa * v0.x + pb * v1.x + pc * v2.x + pdd * v3.x;
        acc.y += pa * v0.y + pb * v1.y + pc * v2.y + pdd * v3.y;
        acc.z += pa * v0.z + pb * v1.z + pc * v2.z + pdd * v3.z;
        acc.w += pa * v0.w + pb * v1.w + pc * v2.w + pdd * v3.w;
    }
    for (; e < e1; ++e) {
        int s0 = srcs[e];
        uint4 r0 = kv4[(size_t)s0 * 32 + l];
        float4 k0 = cvt4(make_uint2(r0.x, r0.y)), v0 = cvt4(make_uint2(r0.z, r0.w));
        float sa = qv.x * k0.x + qv.y * k0.y + qv.z * k0.z + qv.w * k0.w;
        sa += __shfl_xor(sa, 1);
        sa += __shfl_xor(sa, 2);
        sa += __shfl_xor(sa, 4);
        float pa = __expf(sa * SC);
        z += pa;
        acc.x += pa * v0.x; acc.y += pa * v0.y;
        acc.z += pa * v0.z; acc.w += pa * v0.w;
    }

    float inv = 1.f / (z + 1e-16f);
    float4 o = reinterpret_cast<float4*>(out)[(size_t)node * 32 + l];
    o.x += acc.x * inv; o.y += acc.y * inv;
    o.z += acc.z * inv; o.w += acc.w * inv;
    reinterpret_cast<float4*>(out)[(size_t)node * 32 + l] = o;
}

// ---------------------------------------------------------------------------
extern "C" void kernel_launch(void* const* d_in, const int* in_sizes, int n_in,
                              void* d_out, int out_size, void* d_ws, size_t ws_size,
                              hipStream_t stream)
{
    const float* x   = (const float*)d_in[0];
    const int*   ei  = (const int*)d_in[1];     // int32 on device (harness contract)
    const float* Wq  = (const float*)d_in[2];
    const float* bq  = (const float*)d_in[3];
    const float* Wk  = (const float*)d_in[4];
    const float* bk  = (const float*)d_in[5];
    const float* Wv  = (const float*)d_in[6];
    const float* bv  = (const float*)d_in[7];
    const float* Wsk = (const float*)d_in[8];
    const float* bsk = (const float*)d_in[9];
    float* out = (float*)d_out;

    const int N = in_sizes[0] / DIN;
    const int E = in_sizes[1] / 2;
    const int nb = (N + NPB - 1) / NPB;          // 391 buckets for N=100k
    const int nch = (N + CHUNK - 1) / CHUNK;     // 25 chunks

    // workspace: qh | kvh | wt | pairs | sorted | counts | rowptr |
    //            bar | bcnt | boff | bcur | partials | chunkoff
    _Float16* qh  = (_Float16*)d_ws;
    _Float16* kvh = qh + (size_t)N * DIN;        // N*256 halves
    _Float16* wt  = kvh + (size_t)N * 256;       // 128 KB
    uint2* pairs  = (uint2*)(wt + 4 * 16384);    // E * 8B
    int* sorted   = (int*)(pairs + (size_t)E);
    int* counts   = sorted + E;
    int* rowptr   = counts + N;
    int* bar      = rowptr + (N + 1);            // 8 barrier counters
    int* bcnt     = bar + 8;
    int* boff     = bcnt + 512;
    int* bcur     = boff + 513;
    int* partials = bcur + 512;
    int* chunkoff = partials + 256;

    // zero bar[8] + bcnt[512] in one memset (contiguous)
    hipMemsetAsync(bar, 0, 520 * sizeof(int), stream);

    coop_csr<<<CSR_GRID, 256, 0, stream>>>(
        Wq, Wk, Wv, Wsk, wt, ei, pairs, sorted, counts, rowptr,
        bar, bcnt, boff, bcur, partials, chunkoff, E, N, nb, nch);

    qkvs_mfma<<<(N + MT - 1) / MT, 256, 0, stream>>>(
        x, wt, bq, bk, bv, bsk, qh, kvh, out, N);

    int ab = (N * 32 + 255) / 256;
    node_aggregate<<<ab, 256, 0, stream>>>(qh, kvh, rowptr, sorted, out, N);
}

// Round 8
// 526.416 us; speedup vs baseline: 1.8112x; 1.8112x over previous
//
#include <hip/hip_runtime.h>

#define DIN 128
#define NHEADS 4
#define CH 32
#define MT 128          // GEMM rows per block
#define NPB 256         // nodes per bucket (bucket = dst >> 8)
#define EPB_IT 25       // edges per thread in bucket_scatter (block chunk: 6400)

typedef _Float16 h8 __attribute__((ext_vector_type(8)));
typedef float f4 __attribute__((ext_vector_type(4)));

// ---------------------------------------------------------------------------
// Kernel 1: MFMA GEMM, cvt fused — reads x fp32, converts during LDS staging;
// loops 4 mats per block (A-tile staged once). mats 1/2 write interleaved kv.
// (verified in R7: same absmax as split version)
// ---------------------------------------------------------------------------
__global__ __launch_bounds__(256) void qkvs_mfma(
    const float* __restrict__ x, const float* __restrict__ Wq,
    const float* __restrict__ Wk, const float* __restrict__ Wv,
    const float* __restrict__ Wsk,
    const float* __restrict__ bq, const float* __restrict__ bk,
    const float* __restrict__ bv, const float* __restrict__ bsk,
    _Float16* __restrict__ wt,   // scratch: only block 0 fills it? no—see below
    _Float16* __restrict__ qh, _Float16* __restrict__ kvh,
    float* __restrict__ outskip, int N)
{
    // NOTE: W is transposed on the fly into registers via strided fp32 loads?
    // No — B frags need Wt[n][k] contiguous in k. We read W[k][n] columns as
    // 8 strided fp32 loads per frag; W is 64KB/mat -> L1/L2 resident, so the
    // strided reads are cache hits after first touch. Simpler than a prep
    // pass and saves one dispatch + one global round-trip.
    __shared__ _Float16 As[MT * 128];            // 32 KB
    const int t = threadIdx.x;
    const int rowBase = blockIdx.x * MT;

    const float4* x4 = reinterpret_cast<const float4*>(x);
    for (int i = t; i < MT * 16; i += 256) {
        int r  = i >> 4;
        int c8 = i & 15;
        h8 hv = {};
        int gr = rowBase + r;
        if (gr < N) {
            float4 f0 = x4[(size_t)gr * 32 + c8 * 2];
            float4 f1 = x4[(size_t)gr * 32 + c8 * 2 + 1];
            hv[0] = (_Float16)f0.x; hv[1] = (_Float16)f0.y;
            hv[2] = (_Float16)f0.z; hv[3] = (_Float16)f0.w;
            hv[4] = (_Float16)f1.x; hv[5] = (_Float16)f1.y;
            hv[6] = (_Float16)f1.z; hv[7] = (_Float16)f1.w;
        }
        *reinterpret_cast<h8*>(&As[r * 128 + ((c8 ^ (r & 7)) << 3)]) = hv;
    }
    __syncthreads();

    const int wid  = t >> 6;
    const int l    = t & 63;
    const int lm   = l & 15;
    const int quad = l >> 4;

    const float* Wm[4] = {Wq, Wk, Wv, Wsk};
    const float* bm[4] = {bq, bk, bv, bsk};

    for (int mat = 0; mat < 4; ++mat) {
        const float* __restrict__ W = Wm[mat];

        f4 acc[2][8];
        #pragma unroll
        for (int ms = 0; ms < 2; ++ms)
            #pragma unroll
            for (int nt = 0; nt < 8; ++nt)
                acc[ms][nt] = (f4){0.f, 0.f, 0.f, 0.f};

        #pragma unroll
        for (int kq = 0; kq < 4; ++kq) {
            const int c8 = kq * 4 + quad;
            const int k0 = c8 << 3;
            h8 a0 = *reinterpret_cast<const h8*>(
                &As[(wid * 32 + lm) * 128 + ((c8 ^ (lm & 7)) << 3)]);
            h8 a1 = *reinterpret_cast<const h8*>(
                &As[(wid * 32 + 16 + lm) * 128 + ((c8 ^ (lm & 7)) << 3)]);
            #pragma unroll
            for (int nt = 0; nt < 8; ++nt) {
                int col = nt * 16 + lm;
                h8 bfr;
                #pragma unroll
                for (int j = 0; j < 8; ++j)
                    bfr[j] = (_Float16)W[(size_t)(k0 + j) * 128 + col];
                acc[0][nt] = __builtin_amdgcn_mfma_f32_16x16x32_f16(a0, bfr, acc[0][nt], 0, 0, 0);
                acc[1][nt] = __builtin_amdgcn_mfma_f32_16x16x32_f16(a1, bfr, acc[1][nt], 0, 0, 0);
            }
        }

        const float* bias = bm[mat];

        #pragma unroll
        for (int ms = 0; ms < 2; ++ms) {
            #pragma unroll
            for (int nt = 0; nt < 8; ++nt) {
                int col = nt * 16 + lm;
                float bsv = bias[col];
                #pragma unroll
                for (int i2 = 0; i2 < 4; ++i2) {
                    int row = rowBase + wid * 32 + ms * 16 + quad * 4 + i2;
                    if (row < N) {
                        float val = acc[ms][nt][i2] + bsv;
                        if (mat == 3)
                            outskip[(size_t)row * 128 + col] = val;
                        else if (mat == 0)
                            qh[(size_t)row * 128 + col] = (_Float16)val;
                        else {
                            size_t off = (size_t)row * 256 + ((col >> 2) << 3)
                                       + (col & 3) + ((mat == 2) ? 4 : 0);
                            kvh[off] = (_Float16)val;
                        }
                    }
                }
            }
        }
    }
}

// ---------------------------------------------------------------------------
// Bucketed CSR build (4 dispatches).  bucket b = nodes [b*256, b*256+256)
// ---------------------------------------------------------------------------
__global__ __launch_bounds__(256) void bucket_hist(
    const int* __restrict__ ei, int* __restrict__ bcnt, int E, int nb)
{
    __shared__ int lds[512];
    for (int b = threadIdx.x; b < nb; b += 256) lds[b] = 0;
    __syncthreads();
    for (long long i = (long long)blockIdx.x * 256 + threadIdx.x; i < E;
         i += (long long)gridDim.x * 256)
        atomicAdd(&lds[ei[(size_t)E + i] >> 8], 1);
    __syncthreads();
    for (int b = threadIdx.x; b < nb; b += 256)
        if (lds[b]) atomicAdd(&bcnt[b], lds[b]);
}

// exclusive scan of bucket counts (1 block, nb <= 512). boff doubles as the
// cross-bucket rowptr offset (CHUNK == NPB insight).
__global__ __launch_bounds__(512) void scan_buckets(
    const int* __restrict__ bcnt, int* __restrict__ boff,
    int* __restrict__ bcur, int nb)
{
    __shared__ int ws[8];
    int t = threadIdx.x, lane = t & 63, wid = t >> 6;
    int v = (t < nb) ? bcnt[t] : 0;
    int s = v;
    #pragma unroll
    for (int off = 1; off < 64; off <<= 1) {
        int n = __shfl_up(s, off);
        if (lane >= off) s += n;
    }
    if (lane == 63) ws[wid] = s;
    __syncthreads();
    int add = 0;
    for (int w = 0; w < wid; ++w) add += ws[w];
    int excl = s - v + add;
    if (t < nb) { boff[t] = excl; bcur[t] = excl; }
    if (t == nb - 1) boff[nb] = excl + v;
}

// scatter (src,dst) pairs into bucket regions, coalesced runs
__global__ __launch_bounds__(256) void bucket_scatter(
    const int* __restrict__ ei, int* __restrict__ bcur,
    uint2* __restrict__ pairs, int E, int nb)
{
    __shared__ int cnt[512];
    int t = threadIdx.x;
    for (int b = t; b < nb; b += 256) cnt[b] = 0;
    __syncthreads();

    long long e0 = (long long)blockIdx.x * (256 * EPB_IT);
    int ps[EPB_IT], pd[EPB_IT];
    #pragma unroll
    for (int j = 0; j < EPB_IT; ++j) {
        long long e = e0 + j * 256 + t;
        if (e < E) {
            ps[j] = ei[e];
            pd[j] = ei[(size_t)E + e];
            atomicAdd(&cnt[pd[j] >> 8], 1);
        } else pd[j] = -1;
    }
    __syncthreads();
    for (int b = t; b < nb; b += 256) {
        int c = cnt[b];
        if (c) cnt[b] = atomicAdd(&bcur[b], c);
    }
    __syncthreads();
    #pragma unroll
    for (int j = 0; j < EPB_IT; ++j) {
        if (pd[j] >= 0) {
            int pos = atomicAdd(&cnt[pd[j] >> 8], 1);
            pairs[pos] = make_uint2((unsigned)ps[j], (unsigned)pd[j]);
        }
    }
}

// Fused: per-node counts (LDS) -> LDS scan -> rowptr -> place srcs.
// Replaces R6's bucket_counts + chunk_sums + scan_chunks + scan_write +
// bucket_place: rowptr[node] = boff[bucket] + within-bucket exclusive prefix.
__global__ __launch_bounds__(256) void bucket_csr(
    const uint2* __restrict__ pairs, const int* __restrict__ boff,
    int* __restrict__ rowptr, int* __restrict__ sorted, int N, int E, int nb)
{
    __shared__ int cnt[NPB];
    __shared__ int ws[4];
    int b = blockIdx.x, t = threadIdx.x;
    cnt[t] = 0;
    __syncthreads();
    int s = boff[b], e = boff[b + 1];
    for (int i = s + t; i < e; i += 256)
        atomicAdd(&cnt[pairs[i].y & (NPB - 1)], 1);
    __syncthreads();

    // exclusive scan of the 256 per-node counts
    int v = cnt[t];
    int lane = t & 63, wid = t >> 6;
    int incl = v;
    #pragma unroll
    for (int off = 1; off < 64; off <<= 1) {
        int n = __shfl_up(incl, off);
        if (lane >= off) incl += n;
    }
    if (lane == 63) ws[wid] = incl;
    __syncthreads();
    int add = boff[b];
    for (int w = 0; w < wid; ++w) add += ws[w];
    int excl = incl - v + add;        // global CSR start for this node

    int node = b * NPB + t;
    if (node < N) rowptr[node] = excl;
    if (b == 0 && t == 0) rowptr[N] = E;

    // reuse cnt[] as cursors (each thread touches only its own slot here)
    cnt[t] = excl;
    __syncthreads();
    for (int i = s + t; i < e; i += 256) {
        uint2 pr = pairs[i];
        int pos = atomicAdd(&cnt[pr.y & (NPB - 1)], 1);
        sorted[pos] = (int)pr.x;
    }
}

// ---------------------------------------------------------------------------
// Fused logits + softmax + aggregation (unchanged control from R6)
// ---------------------------------------------------------------------------
__device__ inline float4 cvt4(uint2 r) {
    union { uint2 u; _Float16 h[4]; } c;
    c.u = r;
    return make_float4((float)c.h[0], (float)c.h[1], (float)c.h[2], (float)c.h[3]);
}

__global__ __launch_bounds__(256) void node_aggregate(
    const _Float16* __restrict__ q, const _Float16* __restrict__ kv,
    const int* __restrict__ rowptr, const int* __restrict__ srcs,
    float* __restrict__ out, int N)
{
    int gid  = blockIdx.x * 256 + threadIdx.x;
    int node = gid >> 5;
    if (node >= N) return;
    int l = gid & 31;

    float4 qv = cvt4(reinterpret_cast<const uint2*>(q + (size_t)node * 128)[l]);
    float4 acc = make_float4(0.f, 0.f, 0.f, 0.f);
    float z = 0.f;

    const uint4* kv4 = reinterpret_cast<const uint4*>(kv);
    const float SC = 0.17677669529663687f;   // 1/sqrt(32)
    int e0 = rowptr[node], e1 = rowptr[node + 1];
    int e = e0;
    for (; e + 4 <= e1; e += 4) {
        int s0 = srcs[e], s1 = srcs[e + 1], s2 = srcs[e + 2], s3 = srcs[e + 3];
        uint4 r0 = kv4[(size_t)s0 * 32 + l];
        uint4 r1 = kv4[(size_t)s1 * 32 + l];
        uint4 r2 = kv4[(size_t)s2 * 32 + l];
        uint4 r3 = kv4[(size_t)s3 * 32 + l];
        float4 k0 = cvt4(make_uint2(r0.x, r0.y)), v0 = cvt4(make_uint2(r0.z, r0.w));
        float4 k1 = cvt4(make_uint2(r1.x, r1.y)), v1 = cvt4(make_uint2(r1.z, r1.w));
        float4 k2 = cvt4(make_uint2(r2.x, r2.y)), v2 = cvt4(make_uint2(r2.z, r2.w));
        float4 k3 = cvt4(make_uint2(r3.x, r3.y)), v3 = cvt4(make_uint2(r3.z, r3.w));
        float sa = qv.x * k0.x + qv.y * k0.y + qv.z * k0.z + qv.w * k0.w;
        float sb = qv.x * k1.x + qv.y * k1.y + qv.z * k1.z + qv.w * k1.w;
        float sc = qv.x * k2.x + qv.y * k2.y + qv.z * k2.z + qv.w * k2.w;
        float sd = qv.x * k3.x + qv.y * k3.y + qv.z * k3.z + qv.w * k3.w;
        sa += __shfl_xor(sa, 1); sb += __shfl_xor(sb, 1);
        sc += __shfl_xor(sc, 1); sd += __shfl_xor(sd, 1);
        sa += __shfl_xor(sa, 2); sb += __shfl_xor(sb, 2);
        sc += __shfl_xor(sc, 2); sd += __shfl_xor(sd, 2);
        sa += __shfl_xor(sa, 4); sb += __shfl_xor(sb, 4);
        sc += __shfl_xor(sc, 4); sd += __shfl_xor(sd, 4);
        float pa = __expf(sa * SC), pb = __expf(sb * SC);
        float pc = __expf(sc * SC), pdd = __expf(sd * SC);
        z += (pa + pb) + (pc + pdd);
        acc.x += pa * v0.x + pb * v1.x + pc * v2.x + pdd * v3.x;
        acc.y += pa * v0.y + pb * v1.y + pc * v2.y + pdd * v3.y;
        acc.z += pa * v0.z + pb * v1.z + pc * v2.z + pdd * v3.z;
        acc.w += pa * v0.w + pb * v1.w + pc * v2.w + pdd * v3.w;
    }
    for (; e < e1; ++e) {
        int s0 = srcs[e];
        uint4 r0 = kv4[(size_t)s0 * 32 + l];
        float4 k0 = cvt4(make_uint2(r0.x, r0.y)), v0 = cvt4(make_uint2(r0.z, r0.w));
        float sa = qv.x * k0.x + qv.y * k0.y + qv.z * k0.z + qv.w * k0.w;
        sa += __shfl_xor(sa, 1);
        sa += __shfl_xor(sa, 2);
        sa += __shfl_xor(sa, 4);
        float pa = __expf(sa * SC);
        z += pa;
        acc.x += pa * v0.x; acc.y += pa * v0.y;
        acc.z += pa * v0.z; acc.w += pa * v0.w;
    }

    float inv = 1.f / (z + 1e-16f);
    float4 o = reinterpret_cast<float4*>(out)[(size_t)node * 32 + l];
    o.x += acc.x * inv; o.y += acc.y * inv;
    o.z += acc.z * inv; o.w += acc.w * inv;
    reinterpret_cast<float4*>(out)[(size_t)node * 32 + l] = o;
}

// ---------------------------------------------------------------------------
extern "C" void kernel_launch(void* const* d_in, const int* in_sizes, int n_in,
                              void* d_out, int out_size, void* d_ws, size_t ws_size,
                              hipStream_t stream)
{
    const float* x   = (const float*)d_in[0];
    const int*   ei  = (const int*)d_in[1];     // int32 on device (harness contract)
    const float* Wq  = (const float*)d_in[2];
    const float* bq  = (const float*)d_in[3];
    const float* Wk  = (const float*)d_in[4];
    const float* bk  = (const float*)d_in[5];
    const float* Wv  = (const float*)d_in[6];
    const float* bv  = (const float*)d_in[7];
    const float* Wsk = (const float*)d_in[8];
    const float* bsk = (const float*)d_in[9];
    float* out = (float*)d_out;

    const int N = in_sizes[0] / DIN;
    const int E = in_sizes[1] / 2;
    const int nb = (N + NPB - 1) / NPB;          // 391 buckets for N=100k

    // workspace: qh | kvh | wt(spare) | pairs | sorted | rowptr | bcnt | boff | bcur
    _Float16* qh  = (_Float16*)d_ws;
    _Float16* kvh = qh + (size_t)N * DIN;        // N*256 halves
    _Float16* wt  = kvh + (size_t)N * 256;       // reserved (unused this round)
    uint2* pairs  = (uint2*)(wt + 4 * 16384);    // E * 8B
    int* sorted   = (int*)(pairs + (size_t)E);
    int* rowptr   = sorted + E;
    int* bcnt     = rowptr + (N + 1);
    int* boff     = bcnt + 512;
    int* bcur     = boff + 513;

    hipMemsetAsync(bcnt, 0, 512 * sizeof(int), stream);

    qkvs_mfma<<<(N + MT - 1) / MT, 256, 0, stream>>>(
        x, Wq, Wk, Wv, Wsk, bq, bk, bv, bsk, wt, qh, kvh, out, N);

    bucket_hist<<<256, 256, 0, stream>>>(ei, bcnt, E, nb);
    scan_buckets<<<1, 512, 0, stream>>>(bcnt, boff, bcur, nb);
    int sb = (E + 256 * EPB_IT - 1) / (256 * EPB_IT);
    bucket_scatter<<<sb, 256, 0, stream>>>(ei, bcur, pairs, E, nb);
    bucket_csr<<<nb, 256, 0, stream>>>(pairs, boff, rowptr, sorted, N, E, nb);

    int ab = (N * 32 + 255) / 256;
    node_aggregate<<<ab, 256, 0, stream>>>(qh, kvh, rowptr, sorted, out, N);
}